// Round 7
// baseline (138.676 us; speedup 1.0000x reference)
//
#include <hip/hip_runtime.h>
#include <stdint.h>

// Problem constants (B=2048, N=16, T=1024)
#define T_STEPS 1024
#define NWORDS  256          // u64 mask words per batch (4 timesteps packed per word)
#define NB      8            // batches per scan block
#define SCAN_BLOCK (NB * 16) // 128 threads: 8 batches x 16 output neurons

// ---------------------------------------------------------------------------
// Kernel 1: compress binary spike floats -> 16-bit masks, 4 timesteps per u64.
// Fully coalesced float4 reads; owns the HBM-bound 128 MiB read (~21 us).
// ---------------------------------------------------------------------------
__global__ __launch_bounds__(256) void k_maskify(const float* __restrict__ spike,
                                                 unsigned long long* __restrict__ masks) {
    const int b  = blockIdx.x;
    const int tc = threadIdx.x;  // handles t = 4*tc .. 4*tc+3
    const float4* sp = reinterpret_cast<const float4*>(spike) + (size_t)b * (16 * NWORDS);
    unsigned int m0 = 0, m1 = 0, m2 = 0, m3 = 0;
#pragma unroll
    for (int i = 0; i < 16; ++i) {
        float4 v = sp[i * NWORDS + tc];
        m0 |= (v.x >= 0.5f) ? (1u << i) : 0u;
        m1 |= (v.y >= 0.5f) ? (1u << i) : 0u;
        m2 |= (v.z >= 0.5f) ? (1u << i) : 0u;
        m3 |= (v.w >= 0.5f) ? (1u << i) : 0u;
    }
    masks[(size_t)b * NWORDS + tc] =
        (unsigned long long)m0 | ((unsigned long long)m1 << 16) |
        ((unsigned long long)m2 << 32) | ((unsigned long long)m3 << 48);
}

// ---------------------------------------------------------------------------
// Kernel 2: CUBA LIF scan, fp64 state (absmax was 0.0 vs the f64 numpy ref;
// every change below preserves the EXACT association tree (z0+z1)+(z2+z3)).
//
// R4 changes:
//  - __launch_bounds__(128,1): we are structurally 1 wave/SIMD (512 waves on
//    1024 SIMDs), so give the allocator the full VGPR file. R3's VGPR=68
//    proved the prefetch buffers were never register-resident.
//  - Byte tables ztab8[2][256][16] (64 KiB LDS): per step 2 ds_read_b64 + 1
//    add replaces 4 reads + 3 adds. Entry = (lo-nibble ordered sum) +
//    (hi-nibble ordered sum)  ==  z_{2s} + z_{2s+1} exactly.
//  - Depth-2-word pipeline: loads for word tg+2 are issued before computing
//    word tg (~200 cyc issue->use); mask words held 2-3 ahead in registers.
// ---------------------------------------------------------------------------
__global__ __launch_bounds__(SCAN_BLOCK, 1) void k_scan(const float* __restrict__ W,
                                                        const unsigned long long* __restrict__ masks,
                                                        const float* __restrict__ spike,
                                                        float* __restrict__ out) {
    __shared__ double ztab8[2][256][16];            // [byteseg][byte][o]  (64 KiB)
    __shared__ unsigned long long mlds[NB][NWORDS]; // 16 KiB
    __shared__ float outtab[17];

    const int tid = threadIdx.x;
    const int bb  = tid >> 4;   // local batch 0..NB-1
    const int o   = tid & 15;   // output neuron

    // --- Build byte tables. Thread's o == e&15 for e = tid + k*128, so each
    // thread only needs W row o (16 values, f64) in registers.
    {
        double w[16];
#pragma unroll
        for (int j = 0; j < 16; ++j) w[j] = (double)W[o * 16 + j];
        for (int k = 0; k < 64; ++k) {
            const int e    = tid + k * SCAN_BLOCK;
            const int byte = (e >> 4) & 255;
            const int s    = e >> 12;
            // lo-nibble ordered sum (== z_{2s}), hi-nibble ordered sum (== z_{2s+1})
            double slo = 0.0, shi = 0.0;
#pragma unroll
            for (int j = 0; j < 4; ++j) slo += (byte & (1 << j))  ? w[8 * s + j]     : 0.0;
#pragma unroll
            for (int j = 0; j < 4; ++j) shi += (byte & (16 << j)) ? w[8 * s + 4 + j] : 0.0;
            ztab8[s][byte][o] = slo + shi;          // = z_{2s} + z_{2s+1}
        }
    }
    // out[k] = 2^16 * cosh(1)^k
    if (tid < 17) {
        const double ln2  = 0.69314718055994530941723212145818;
        const double l2c1 = log(2.0 * cosh(1.0));
        outtab[tid] = (float)exp((16.0 - (double)tid) * ln2 + (double)tid * l2c1);
    }

    if (masks != nullptr) {
        const unsigned long long* src = masks + (size_t)blockIdx.x * NB * NWORDS;
        for (int e = tid; e < NB * NWORDS; e += SCAN_BLOCK)
            ((unsigned long long*)mlds)[e] = src[e];
    } else {
        // Fallback (ws too small): build masks from raw spikes in-kernel.
        const int part = tid & 15;
        const float4* spb = reinterpret_cast<const float4*>(spike) +
                            (size_t)(blockIdx.x * NB + bb) * (16 * NWORDS);
        for (int w = 0; w < 16; ++w) {
            const int tc = part * 16 + w;
            unsigned int m0 = 0, m1 = 0, m2 = 0, m3 = 0;
#pragma unroll
            for (int i = 0; i < 16; ++i) {
                float4 v = spb[i * NWORDS + tc];
                m0 |= (v.x >= 0.5f) ? (1u << i) : 0u;
                m1 |= (v.y >= 0.5f) ? (1u << i) : 0u;
                m2 |= (v.z >= 0.5f) ? (1u << i) : 0u;
                m3 |= (v.w >= 0.5f) ? (1u << i) : 0u;
            }
            mlds[bb][tc] = (unsigned long long)m0 | ((unsigned long long)m1 << 16) |
                           ((unsigned long long)m2 << 32) | ((unsigned long long)m3 << 48);
        }
    }
    __syncthreads();

    double c = 0.0, v = 0.0;
    const int b = blockIdx.x * NB + bb;
    float4* outp4 = reinterpret_cast<float4*>(out + (size_t)b * T_STEPS);
    const unsigned long long* mrow = &mlds[bb][0];
    const int grp_sh = tid & 48;     // (lane/16)*16 : this batch-group's ballot slot
    const bool writer = (o == 0);

    // Issue the 8 byte-table loads for one mask word (static indices -> VGPRs).
#define ISSUE(L, MW)                                                            \
    {                                                                           \
        const unsigned long long _mw = (MW);                                    \
        _Pragma("unroll")                                                       \
        for (int j = 0; j < 4; ++j) {                                           \
            const unsigned int m = (unsigned int)(_mw >> (16 * j)) & 0xFFFFu;   \
            L[2 * j + 0] = ztab8[0][m & 255][o];                                \
            L[2 * j + 1] = ztab8[1][(m >> 8) & 255][o];                         \
        }                                                                       \
    }

    // Off-chain: z[j] = (z0+z1) + (z2+z3), same tree as R1/R3.
#define SUMZ(Z, L)                                                              \
    _Pragma("unroll")                                                           \
    for (int j = 0; j < 4; ++j) Z[j] = L[2 * j + 0] + L[2 * j + 1];

    // 4 recurrence steps; numerics identical to R1: fma(c,0.75,z), fma(v,0.97,c).
#define STEPS(Z, TG)                                                            \
    {                                                                           \
        float4 ow;                                                              \
        _Pragma("unroll")                                                       \
        for (int j = 0; j < 4; ++j) {                                           \
            c = fma(c, 0.75, Z[j]);                                             \
            v = fma(v, 0.97, c);                                                \
            const bool s = (v >= 1.25);                                         \
            const unsigned long long bal = __ballot(s);                         \
            v = s ? 0.0 : v;                                                    \
            const float oval = outtab[(int)__popcll((bal >> grp_sh) & 0xFFFFull)]; \
            if (j == 0) ow.x = oval; else if (j == 1) ow.y = oval;              \
            else if (j == 2) ow.z = oval; else ow.w = oval;                     \
        }                                                                       \
        if (writer) outp4[TG] = ow;                                             \
    }

    double LA[8], LB[8], ZA[4], ZB[4];
    // Prologue: masks 2-3 ahead in regs; loads for words 0,1 in flight.
    unsigned long long mw_a = mrow[2], mw_b = mrow[3];
    ISSUE(LA, mrow[0]);
    ISSUE(LB, mrow[1]);

    for (int tg = 0; tg < NWORDS - 4; tg += 2) {
        SUMZ(ZA, LA);              // waits on word tg (issued 1 full iter ago)
        ISSUE(LA, mw_a);           // loads for word tg+2
        mw_a = mrow[tg + 4];       // refresh mask (tg+4 <= 254)
        STEPS(ZA, tg);
        SUMZ(ZB, LB);
        ISSUE(LB, mw_b);           // loads for word tg+3
        mw_b = mrow[tg + 5];       // tg+5 <= 255
        STEPS(ZB, tg + 1);
    }
    // Epilogue: LA=word 252, LB=253, mw_a=m[254], mw_b=m[255]
    SUMZ(ZA, LA); ISSUE(LA, mw_a); STEPS(ZA, NWORDS - 4);
    SUMZ(ZB, LB); ISSUE(LB, mw_b); STEPS(ZB, NWORDS - 3);
    SUMZ(ZA, LA); STEPS(ZA, NWORDS - 2);
    SUMZ(ZB, LB); STEPS(ZB, NWORDS - 1);

#undef ISSUE
#undef SUMZ
#undef STEPS
}

extern "C" void kernel_launch(void* const* d_in, const int* in_sizes, int n_in,
                              void* d_out, int out_size, void* d_ws, size_t ws_size,
                              hipStream_t stream) {
    const float* spike = (const float*)d_in[0];
    const float* W     = (const float*)d_in[1];
    float* out         = (float*)d_out;

    const int B = in_sizes[0] / (16 * T_STEPS);  // 2048

    const size_t mask_bytes = (size_t)B * NWORDS * sizeof(unsigned long long);  // 4 MiB
    unsigned long long* masks = nullptr;
    if (ws_size >= mask_bytes) {
        masks = (unsigned long long*)d_ws;
        k_maskify<<<B, 256, 0, stream>>>(spike, masks);
    }
    k_scan<<<B / NB, SCAN_BLOCK, 0, stream>>>(W, masks, spike, out);
}